// Round 12
// baseline (195.019 us; speedup 1.0000x reference)
//
#include <hip/hip_runtime.h>
#include <math.h>

// fp16-MFMA flash attention (no-max softmax), S=8192, D=128, fp32 in/out.
// R25 = R22 (best attn_main, 45.4us) + attn_norm FUSED via in-kernel grid
// barrier (3 -> 2 dispatches). Evidence: R24 eliminated the prep dispatch
// and total-minus-attn dropped 64.4 -> 51.6us (~13us pure per-dispatch
// overhead) even though its in-kernel staging was a net loss. R25 fuses the
// CHEAP kernel instead: norm's 36MB reduce (~7us spread over 256 CUs).
// Safety: R22's grid is 256 blocks x 1 block/CU (96KB LDS) -- ALL blocks
// co-resident by construction => atomic-counter grid barrier cannot
// deadlock. Protocol: partial stores -> __threadfence (buffer_wbl2, cross-
// XCD writeback) -> syncthreads -> tid0 release-fetch_add + acquire-poll
// (==256) -> syncthreads -> each block normalizes rows [blk*32, blk*32+32)
// (attn_norm math verbatim, coalesced). cnt zeroed by prep t==0 each replay.
// Stale-L1 audit: only lines a CU re-reads are its own writes (safe).
// Kept from R22: ring-3 LDS pipeline QK(t)||PV(t-1)||SM(t), carried P,
// permlane32_swap softmax, setprio, transposed-S fp16 QK^T, async
// global_load_lds staging, 8-slice partials. Fallback path: old 3-dispatch
// atomic structure, untouched.
// Graveyard: R8/R11 fusion(old), R9/R6 16-slice, R10 direct L2->reg,
// R14/R17/R20 64q/wave (spills), R15 stagger, R16 phase rotation, R18
// restructure (correctness), R19 4 waves/SIMD, R21 traffic cut (neutral),
// R23 producer/consumer (2.8x regression), R24 prep fusion (staging on
// critical path, +21.6us attn).

typedef _Float16 f16x8 __attribute__((ext_vector_type(8)));
typedef float    f32x16 __attribute__((ext_vector_type(16)));

constexpr int S_LEN = 8192;
constexpr int D_K   = 128;
constexpr int NSLICE = 8;
constexpr int ITERS2 = (S_LEN / NSLICE) / 64;   // 16 iters of 64-key tiles

// ws: Lpart[8][8192] (256KB) | KV frags (4MB) | Opart[7] x 4MB | cnt
constexpr size_t WS_L_OFF = 0;
constexpr size_t KV_OFF   = 262144;
constexpr size_t PART_OFF = KV_OFF + (size_t)256 * 16384;
constexpr size_t CNT_OFF  = PART_OFF + (size_t)7 * S_LEN * D_K * 4;
constexpr size_t WS_NEED  = CNT_OFF + 64;   // ~32.5 MB

#define CSCALE (0.08838834764831845f * 1.44269504088896340736f)

union UH8 { _Float16 h[8]; uint4 q; f16x8 v; };
union UF4 { unsigned u[4]; uint4 q; f16x8 v; };

__device__ inline void async16(const uint4* g, uint4* l) {
  __builtin_amdgcn_global_load_lds(
      (const __attribute__((address_space(1))) unsigned int*)g,
      (__attribute__((address_space(3))) unsigned int*)l, 16, 0, 0);
}

// ---------------- prep: frag build (+ zero out/ws_l if atomic path) ----------
template <bool ZOUT>
__global__ __launch_bounds__(512) void attn_prep(const float* __restrict__ K,
                                                 const float* __restrict__ V,
                                                 float* __restrict__ out,
                                                 char* __restrict__ ws) {
  const int t = blockIdx.x * 512 + threadIdx.x;
  uint4* KVg = (uint4*)(ws + KV_OFF);
  if (t == 0) *(unsigned*)(ws + CNT_OFF) = 0u;   // reset grid-barrier counter
  if (t < 131072) {
    // K frag: lane holds K[key=lane&31][d0..d0+7], d0 = s*16 + (lane>>5)*8
    int kt = t >> 9, idx = t & 511;
    int lane = idx & 63, s = idx >> 6;
    int key = kt * 32 + (lane & 31);
    int d0  = s * 16 + (lane >> 5) * 8;
    const float4* src = (const float4*)(K + (size_t)key * D_K + d0);
    float4 a = src[0], b = src[1];
    float f[8] = {a.x, a.y, a.z, a.w, b.x, b.y, b.z, b.w};
    UH8 h;
    #pragma unroll
    for (int j = 0; j < 8; ++j) h.h[j] = (_Float16)f[j];
    KVg[(size_t)kt * 1024 + idx] = h.q;
  } else if (t < 262144) {
    // V frag: lane holds V[kb..kb+7][d], d = c*32 + (lane&31)
    int g = t - 131072;
    int kt = g >> 9, idx = g & 511;
    int lane = idx & 63, c = (idx >> 6) & 3, kstep = idx >> 8;
    int d  = c * 32 + (lane & 31);
    int kb = kt * 32 + kstep * 16 + (lane >> 5) * 8;
    UH8 h;
    #pragma unroll
    for (int j = 0; j < 8; ++j) h.h[j] = (_Float16)V[(size_t)(kb + j) * D_K + d];
    KVg[(size_t)kt * 1024 + 512 + idx] = h.q;
  } else if (ZOUT && t < 327680) {
    int i = t - 262144;  // zero out: 65536 threads x 4 float4
    float4 z = make_float4(0.f, 0.f, 0.f, 0.f);
    float4* o4 = (float4*)out;
    #pragma unroll
    for (int j = 0; j < 4; ++j) o4[(size_t)i * 4 + j] = z;
  } else if (ZOUT && t < 329728) {
    int i = t - 327680;  // zero ws_l: 2048 float4
    ((float4*)(ws + WS_L_OFF))[i] = make_float4(0.f, 0.f, 0.f, 0.f);
  }
}

// QK^T over one 32-key subtile: 8 K-frag ds_reads feeding 2 interleaved
// 4-deep MFMA chains (Sa even d-slices, Sb odd).
__device__ inline void qk32(const uint4* sub, const f16x8* qf, int lane,
                            f32x16& Sa, f32x16& Sb) {
  Sa = f32x16{}; Sb = f32x16{};
  __builtin_amdgcn_s_setprio(1);
  #pragma unroll
  for (int s = 0; s < 4; ++s) {
    f16x8 ka = __builtin_bit_cast(f16x8, sub[(2 * s    ) * 64 + lane]);
    f16x8 kb = __builtin_bit_cast(f16x8, sub[(2 * s + 1) * 64 + lane]);
    Sa = __builtin_amdgcn_mfma_f32_32x32x16_f16(ka, qf[2 * s    ], Sa, 0, 0, 0);
    Sb = __builtin_amdgcn_mfma_f32_32x32x16_f16(kb, qf[2 * s + 1], Sb, 0, 0, 0);
  }
  __builtin_amdgcn_s_setprio(0);
}

// softmax over one 32-key subtile: Sa+Sb -> exp2 -> packed fp16 P frags
// (A0 = keys 0..15, A1 = keys 16..31), accumulating row-sum.
// P transpose via v_permlane32_swap (R15-verified lane mapping).
__device__ inline void softmax32(const f32x16& Sa, const f32x16& Sb,
                                 float& lsum, UF4& A0, UF4& A1) {
  unsigned pk[8];
  #pragma unroll
  for (int i = 0; i < 8; ++i) {
    float p0 = __builtin_amdgcn_exp2f(Sa[2 * i]     + Sb[2 * i]);
    float p1 = __builtin_amdgcn_exp2f(Sa[2 * i + 1] + Sb[2 * i + 1]);
    lsum += p0 + p1;
    pk[i] = __builtin_bit_cast(unsigned, __builtin_amdgcn_cvt_pkrtz(p0, p1));
  }
  auto r0 = __builtin_amdgcn_permlane32_swap((int)pk[0], (int)pk[2], false, false);
  auto r1 = __builtin_amdgcn_permlane32_swap((int)pk[1], (int)pk[3], false, false);
  auto r2 = __builtin_amdgcn_permlane32_swap((int)pk[4], (int)pk[6], false, false);
  auto r3 = __builtin_amdgcn_permlane32_swap((int)pk[5], (int)pk[7], false, false);
  A0.u[0] = (unsigned)r0[0]; A0.u[2] = (unsigned)r0[1];
  A0.u[1] = (unsigned)r1[0]; A0.u[3] = (unsigned)r1[1];
  A1.u[0] = (unsigned)r2[0]; A1.u[2] = (unsigned)r2[1];
  A1.u[1] = (unsigned)r3[0]; A1.u[3] = (unsigned)r3[1];
}

// PV over one 32-key subtile: 8 V-frag ds_reads feeding 8 MFMAs (4 indep O).
__device__ inline void pv32(const uint4* sub, const UF4& A0, const UF4& A1,
                            int lane, f32x16* O) {
  __builtin_amdgcn_s_setprio(1);
  #pragma unroll
  for (int kstep = 0; kstep < 2; ++kstep) {
    f16x8 pf = kstep ? A1.v : A0.v;
    f16x8 v0 = __builtin_bit_cast(f16x8, sub[512 + kstep * 256 +   0 + lane]);
    f16x8 v1 = __builtin_bit_cast(f16x8, sub[512 + kstep * 256 +  64 + lane]);
    f16x8 v2 = __builtin_bit_cast(f16x8, sub[512 + kstep * 256 + 128 + lane]);
    f16x8 v3 = __builtin_bit_cast(f16x8, sub[512 + kstep * 256 + 192 + lane]);
    O[0] = __builtin_amdgcn_mfma_f32_32x32x16_f16(pf, v0, O[0], 0, 0, 0);
    O[1] = __builtin_amdgcn_mfma_f32_32x32x16_f16(pf, v1, O[1], 0, 0, 0);
    O[2] = __builtin_amdgcn_mfma_f32_32x32x16_f16(pf, v2, O[2], 0, 0, 0);
    O[3] = __builtin_amdgcn_mfma_f32_32x32x16_f16(pf, v3, O[3], 0, 0, 0);
  }
  __builtin_amdgcn_s_setprio(0);
}

// ---------------- main attention kernel ----------------
template <bool PARTIAL>
__global__ __launch_bounds__(512, 2)
void attn_main(const float* __restrict__ Qg, float* __restrict__ out,
               char* __restrict__ ws) {
  __shared__ uint4 KV[3][2048];   // ring-3 of 64-key tiles [K 16KB | V 16KB]

  const int tid   = threadIdx.x;
  const int wave  = tid >> 6;     // 0..7
  const int lane  = tid & 63;
  const int lrow  = lane & 31;
  const int lhalf = lane >> 5;

  const int blk = blockIdx.x;
  const int ks  = blk & 7;               // k-slice (XCD-pinned by dispatch % 8)
  const int qb  = blk >> 3;              // 0..31
  const int qw  = qb * 256 + wave * 32;  // wave's 32-row q base

  float* ws_l = (float*)(ws + WS_L_OFF);

  // ---- Q B-frags: lane holds Q[q=lane&31][d=(lane>>5)*8+j + 16s], scaled ----
  f16x8 qf[8];
  {
    const int q = qw + lrow;
    #pragma unroll
    for (int s = 0; s < 8; ++s) {
      const float4* src = (const float4*)(Qg + (size_t)q * D_K + s * 16 + lhalf * 8);
      float4 a = src[0], b = src[1];
      float f[8] = {a.x, a.y, a.z, a.w, b.x, b.y, b.z, b.w};
      UH8 h;
      #pragma unroll
      for (int j = 0; j < 8; ++j) h.h[j] = (_Float16)(f[j] * CSCALE);
      qf[s] = h.v;
    }
  }

  f32x16 O[4] = {f32x16{}, f32x16{}, f32x16{}, f32x16{}};
  float lsum = 0.f;

  const uint4* KVg = (const uint4*)(ws + KV_OFF);
  const size_t sbase = (size_t)ks * 32768;   // slice = 16 tiles x 2048 uint4

  // prologue: stage tile 0 into ring slot 0 (32 KB, 4 async16/thread)
  #pragma unroll
  for (int i = 0; i < 4; ++i)
    async16(KVg + sbase + i * 512 + tid, &KV[0][i * 512 + tid]);

  UF4 C00, C01, C10, C11;   // carried P-frags of tile t-1 (both subtiles)

  int cur = 0, nxt = 1;
  for (int it = 0; it < ITERS2; ++it) {
    __syncthreads();   // tile(it) staging (issued last iter) now complete

    if (it + 1 < ITERS2) {
      const size_t base = sbase + (size_t)(it + 1) * 2048;
      #pragma unroll
      for (int i = 0; i < 4; ++i)
        async16(KVg + base + i * 512 + tid, &KV[nxt][i * 512 + tid]);
    }

    // ---- QK(t): both subtiles, 4 independent dual-S chains ----
    f32x16 Sa0, Sb0, Sa1, Sb1;
    qk32(&KV[cur][0],    qf, lane, Sa0, Sb0);
    qk32(&KV[cur][1024], qf, lane, Sa1, Sb1);

    // ---- PV(t-1): independent of QK(t) -- overlaps QK's drain ----
    if (it) {
      const int prv = (cur == 0) ? 2 : cur - 1;
      pv32(&KV[prv][0],    C00, C01, lane, O);
      pv32(&KV[prv][1024], C10, C11, lane, O);
    }

    // ---- SM(t): VALU overlaps PV(t-1) MFMA drain; P carried to next iter ----
    softmax32(Sa0, Sb0, lsum, C00, C01);
    softmax32(Sa1, Sb1, lsum, C10, C11);

    cur = nxt;
    nxt = (nxt == 2) ? 0 : nxt + 1;
  }
  // epilogue drain: PV of the last tile
  {
    const int prv = (cur == 0) ? 2 : cur - 1;
    pv32(&KV[prv][0],    C00, C01, lane, O);
    pv32(&KV[prv][1024], C10, C11, lane, O);
  }

  // ---- epilogue ----
  lsum += __shfl_xor(lsum, 32);           // combine the two key-halves

  if (PARTIAL) {
    if (lhalf == 0) ws_l[ks * S_LEN + qw + lrow] = lsum;   // plain store
    float* obase = (ks == 0) ? out
                 : (float*)(ws + PART_OFF) + (size_t)(ks - 1) * S_LEN * D_K;
    #pragma unroll
    for (int r = 0; r < 16; ++r) {
      int row = (r & 3) + 8 * (r >> 2) + 4 * lhalf;
      float* dst = obase + (size_t)(qw + row) * D_K + lrow;
      dst[ 0] = O[0][r];
      dst[32] = O[1][r];
      dst[64] = O[2][r];
      dst[96] = O[3][r];
    }

    // ---- in-kernel grid barrier (256 blocks, all co-resident at 1/CU) ----
    unsigned* cnt = (unsigned*)(ws + CNT_OFF);
    __threadfence();        // write back this thread's partial stores (L2 wb)
    __syncthreads();        // whole block's stores fenced
    if (tid == 0) {
      __hip_atomic_fetch_add(cnt, 1u, __ATOMIC_RELEASE, __HIP_MEMORY_SCOPE_AGENT);
      while (__hip_atomic_load(cnt, __ATOMIC_ACQUIRE, __HIP_MEMORY_SCOPE_AGENT) < 256u)
        __builtin_amdgcn_s_sleep(8);
    }
    __syncthreads();        // acquire (L2 inv) by tid0 ordered before reads

    // ---- fused normalization: this block handles rows [blk*32, blk*32+32)
    //      = float4 indices [blk*1024, blk*1024+1024), attn_norm math ----
    {
      const float* lpart = ws_l;
      const float* opart = (const float*)(ws + PART_OFF);
      float4* o4 = (float4*)out;
      #pragma unroll
      for (int j = 0; j < 2; ++j) {
        const int i = blk * 1024 + j * 512 + tid;   // coalesced per j
        const int q = i >> 5;
        float4 acc = o4[i];
        float l = lpart[q];
        #pragma unroll
        for (int s = 1; s <= 7; ++s) {
          float4 p = ((const float4*)opart)[(size_t)(s - 1) * 262144 + i];
          acc.x += p.x; acc.y += p.y; acc.z += p.z; acc.w += p.w;
          l += lpart[s * S_LEN + q];
        }
        float inv = 1.0f / l;
        acc.x *= inv; acc.y *= inv; acc.z *= inv; acc.w *= inv;
        o4[i] = acc;
      }
    }
  } else {
    if (lhalf == 0) atomicAdd(ws_l + qw + lrow, lsum);
    #pragma unroll
    for (int r = 0; r < 16; ++r) {
      int row = (r & 3) + 8 * (r >> 2) + 4 * lhalf;
      float* dst = out + (size_t)(qw + row) * D_K + lrow;
      atomicAdd(dst +  0, O[0][r]);
      atomicAdd(dst + 32, O[1][r]);
      atomicAdd(dst + 64, O[2][r]);
      atomicAdd(dst + 96, O[3][r]);
    }
  }
}

// ---------------- normalize (fallback path only, nparts=0) ----------------
__global__ __launch_bounds__(256) void attn_norm(float* __restrict__ out,
                                                 const float* __restrict__ lpart,
                                                 const float* __restrict__ opart,
                                                 int nparts) {
  int i = blockIdx.x * 256 + threadIdx.x;  // float4 index, 262144 total
  int q = i >> 5;
  float4* o4 = (float4*)out;
  float4 acc = o4[i];
  float l = lpart[q];
  for (int s = 1; s <= nparts; ++s) {
    float4 p = ((const float4*)opart)[(size_t)(s - 1) * 262144 + i];
    acc.x += p.x; acc.y += p.y; acc.z += p.z; acc.w += p.w;
    l += lpart[s * S_LEN + q];
  }
  float inv = 1.0f / l;
  acc.x *= inv; acc.y *= inv; acc.z *= inv; acc.w *= inv;
  o4[i] = acc;
}

extern "C" void kernel_launch(void* const* d_in, const int* in_sizes, int n_in,
                              void* d_out, int out_size, void* d_ws, size_t ws_size,
                              hipStream_t stream) {
  const float* q = (const float*)d_in[0];
  const float* k = (const float*)d_in[1];
  const float* v = (const float*)d_in[2];
  float* out = (float*)d_out;
  char* ws = (char*)d_ws;

  if (ws_size >= WS_NEED) {
    attn_prep<false><<<dim3(512), dim3(512), 0, stream>>>(k, v, out, ws);
    attn_main<true><<<dim3(256), dim3(512), 0, stream>>>(q, out, ws);
    // norm fused into attn_main via grid barrier -- 2 dispatches total
  } else {
    attn_prep<true><<<dim3(645), dim3(512), 0, stream>>>(k, v, out, ws);
    attn_main<false><<<dim3(256), dim3(512), 0, stream>>>(q, out, ws);
    attn_norm<<<dim3(1024), dim3(256), 0, stream>>>(
        out, (const float*)(ws + WS_L_OFF), (const float*)(ws + KV_OFF), 0);
  }
}

// Round 13
// 112.051 us; speedup vs baseline: 1.7404x; 1.7404x over previous
//
#include <hip/hip_runtime.h>
#include <math.h>

// fp16-MFMA flash attention (no-max softmax), S=8192, D=128, fp32 in/out.
// R26 = R22 exact revert (best: 45.4us main / 109.8 total) + ONE isolated
// tweak: s_setprio REMOVED from MFMA clusters. Evidence: m190 measured
// setprio null-to-negative in barrier-locked same-phase structures (ours);
// it entered bundled in R15, never isolated. R25 post-mortem: norm fusion
// regressed 94us -- per-thread __threadfence = 2048 full-L2 wbl2 flushes,
// then fused norm re-read 36MB from HBM latency-bound (~500GB/s) vs the
// separate norm kernel's warm-L2 ~7us. Fusion lever closed (R24: prep
// fusion also net-negative; dispatch overhead worth <=10us, both fusions
// cost more GPU time than saved).
// Final cost model: total = main 45.4 + prep 3.5 + norm 7 + ~54us fixed
// harness overhead. Main: per CU/iter MFMA 2163cy(32%) + LDS 3072cy(45%,
// 8 waves x 32 ds_read_b128, inherently 8x redundant) + VALU 1600(24%)
// ~= 100% serial; every escape measured-closed: more waves -> LDS
// saturates (R19), fewer reads/MFMA -> 128-reg spills (R14/R17/R20),
// traffic cuts off critical path (R21), scheduling null (R15/R16/R23),
// pipeline +4% (R22).
// Kept from R22: ring-3 LDS pipeline QK(t)||PV(t-1)||SM(t), carried P,
// permlane32_swap softmax, transposed-S fp16 QK^T (A=K,B=Q), dual-S 4-deep
// chains, async global_load_lds staging, 8-slice partials + norm kernel.
// Graveyard: R8/R11 fusion, R9/R6 16-slice, R10 direct L2->reg, R14/R17/R20
// 64q/wave (spills), R15 stagger, R16 phase rotation, R18 restructure
// (correctness), R19 4 waves/SIMD, R21 traffic cut (neutral), R23
// producer/consumer (2.8x), R24 prep fusion (+21.6us main), R25 norm fusion
// via grid barrier (wbl2 storm + cold-HBM norm, +94us main).

typedef _Float16 f16x8 __attribute__((ext_vector_type(8)));
typedef float    f32x16 __attribute__((ext_vector_type(16)));

constexpr int S_LEN = 8192;
constexpr int D_K   = 128;
constexpr int NSLICE = 8;
constexpr int ITERS2 = (S_LEN / NSLICE) / 64;   // 16 iters of 64-key tiles

// ws: Lpart[8][8192] fp32 (256 KB) | KV frags (4 MB) | Opart[7] x 4 MB
constexpr size_t WS_L_OFF = 0;
constexpr size_t KV_OFF   = 262144;
constexpr size_t PART_OFF = KV_OFF + (size_t)256 * 16384;
constexpr size_t WS_NEED  = PART_OFF + (size_t)7 * S_LEN * D_K * 4;  // ~32.5 MB

#define CSCALE (0.08838834764831845f * 1.44269504088896340736f)

union UH8 { _Float16 h[8]; uint4 q; f16x8 v; };
union UF4 { unsigned u[4]; uint4 q; f16x8 v; };

__device__ inline void async16(const uint4* g, uint4* l) {
  __builtin_amdgcn_global_load_lds(
      (const __attribute__((address_space(1))) unsigned int*)g,
      (__attribute__((address_space(3))) unsigned int*)l, 16, 0, 0);
}

// ---------------- prep: frag build (+ zero out/ws_l if atomic path) ----------
template <bool ZOUT>
__global__ __launch_bounds__(512) void attn_prep(const float* __restrict__ K,
                                                 const float* __restrict__ V,
                                                 float* __restrict__ out,
                                                 char* __restrict__ ws) {
  const int t = blockIdx.x * 512 + threadIdx.x;
  uint4* KVg = (uint4*)(ws + KV_OFF);
  if (t < 131072) {
    // K frag: lane holds K[key=lane&31][d0..d0+7], d0 = s*16 + (lane>>5)*8
    int kt = t >> 9, idx = t & 511;
    int lane = idx & 63, s = idx >> 6;
    int key = kt * 32 + (lane & 31);
    int d0  = s * 16 + (lane >> 5) * 8;
    const float4* src = (const float4*)(K + (size_t)key * D_K + d0);
    float4 a = src[0], b = src[1];
    float f[8] = {a.x, a.y, a.z, a.w, b.x, b.y, b.z, b.w};
    UH8 h;
    #pragma unroll
    for (int j = 0; j < 8; ++j) h.h[j] = (_Float16)f[j];
    KVg[(size_t)kt * 1024 + idx] = h.q;
  } else if (t < 262144) {
    // V frag: lane holds V[kb..kb+7][d], d = c*32 + (lane&31)
    int g = t - 131072;
    int kt = g >> 9, idx = g & 511;
    int lane = idx & 63, c = (idx >> 6) & 3, kstep = idx >> 8;
    int d  = c * 32 + (lane & 31);
    int kb = kt * 32 + kstep * 16 + (lane >> 5) * 8;
    UH8 h;
    #pragma unroll
    for (int j = 0; j < 8; ++j) h.h[j] = (_Float16)V[(size_t)(kb + j) * D_K + d];
    KVg[(size_t)kt * 1024 + 512 + idx] = h.q;
  } else if (ZOUT && t < 327680) {
    int i = t - 262144;  // zero out: 65536 threads x 4 float4
    float4 z = make_float4(0.f, 0.f, 0.f, 0.f);
    float4* o4 = (float4*)out;
    #pragma unroll
    for (int j = 0; j < 4; ++j) o4[(size_t)i * 4 + j] = z;
  } else if (ZOUT && t < 329728) {
    int i = t - 327680;  // zero ws_l: 2048 float4
    ((float4*)(ws + WS_L_OFF))[i] = make_float4(0.f, 0.f, 0.f, 0.f);
  }
}

// QK^T over one 32-key subtile: 8 K-frag ds_reads feeding 2 interleaved
// 4-deep MFMA chains (Sa even d-slices, Sb odd).
__device__ inline void qk32(const uint4* sub, const f16x8* qf, int lane,
                            f32x16& Sa, f32x16& Sb) {
  Sa = f32x16{}; Sb = f32x16{};
  #pragma unroll
  for (int s = 0; s < 4; ++s) {
    f16x8 ka = __builtin_bit_cast(f16x8, sub[(2 * s    ) * 64 + lane]);
    f16x8 kb = __builtin_bit_cast(f16x8, sub[(2 * s + 1) * 64 + lane]);
    Sa = __builtin_amdgcn_mfma_f32_32x32x16_f16(ka, qf[2 * s    ], Sa, 0, 0, 0);
    Sb = __builtin_amdgcn_mfma_f32_32x32x16_f16(kb, qf[2 * s + 1], Sb, 0, 0, 0);
  }
}

// softmax over one 32-key subtile: Sa+Sb -> exp2 -> packed fp16 P frags
// (A0 = keys 0..15, A1 = keys 16..31), accumulating row-sum.
// P transpose via v_permlane32_swap (R15-verified lane mapping).
__device__ inline void softmax32(const f32x16& Sa, const f32x16& Sb,
                                 float& lsum, UF4& A0, UF4& A1) {
  unsigned pk[8];
  #pragma unroll
  for (int i = 0; i < 8; ++i) {
    float p0 = __builtin_amdgcn_exp2f(Sa[2 * i]     + Sb[2 * i]);
    float p1 = __builtin_amdgcn_exp2f(Sa[2 * i + 1] + Sb[2 * i + 1]);
    lsum += p0 + p1;
    pk[i] = __builtin_bit_cast(unsigned, __builtin_amdgcn_cvt_pkrtz(p0, p1));
  }
  auto r0 = __builtin_amdgcn_permlane32_swap((int)pk[0], (int)pk[2], false, false);
  auto r1 = __builtin_amdgcn_permlane32_swap((int)pk[1], (int)pk[3], false, false);
  auto r2 = __builtin_amdgcn_permlane32_swap((int)pk[4], (int)pk[6], false, false);
  auto r3 = __builtin_amdgcn_permlane32_swap((int)pk[5], (int)pk[7], false, false);
  A0.u[0] = (unsigned)r0[0]; A0.u[2] = (unsigned)r0[1];
  A0.u[1] = (unsigned)r1[0]; A0.u[3] = (unsigned)r1[1];
  A1.u[0] = (unsigned)r2[0]; A1.u[2] = (unsigned)r2[1];
  A1.u[1] = (unsigned)r3[0]; A1.u[3] = (unsigned)r3[1];
}

// PV over one 32-key subtile: 8 V-frag ds_reads feeding 8 MFMAs (4 indep O).
__device__ inline void pv32(const uint4* sub, const UF4& A0, const UF4& A1,
                            int lane, f32x16* O) {
  #pragma unroll
  for (int kstep = 0; kstep < 2; ++kstep) {
    f16x8 pf = kstep ? A1.v : A0.v;
    f16x8 v0 = __builtin_bit_cast(f16x8, sub[512 + kstep * 256 +   0 + lane]);
    f16x8 v1 = __builtin_bit_cast(f16x8, sub[512 + kstep * 256 +  64 + lane]);
    f16x8 v2 = __builtin_bit_cast(f16x8, sub[512 + kstep * 256 + 128 + lane]);
    f16x8 v3 = __builtin_bit_cast(f16x8, sub[512 + kstep * 256 + 192 + lane]);
    O[0] = __builtin_amdgcn_mfma_f32_32x32x16_f16(pf, v0, O[0], 0, 0, 0);
    O[1] = __builtin_amdgcn_mfma_f32_32x32x16_f16(pf, v1, O[1], 0, 0, 0);
    O[2] = __builtin_amdgcn_mfma_f32_32x32x16_f16(pf, v2, O[2], 0, 0, 0);
    O[3] = __builtin_amdgcn_mfma_f32_32x32x16_f16(pf, v3, O[3], 0, 0, 0);
  }
}

// ---------------- main attention kernel ----------------
template <bool PARTIAL>
__global__ __launch_bounds__(512, 2)
void attn_main(const float* __restrict__ Qg, float* __restrict__ out,
               char* __restrict__ ws) {
  __shared__ uint4 KV[3][2048];   // ring-3 of 64-key tiles [K 16KB | V 16KB]

  const int tid   = threadIdx.x;
  const int wave  = tid >> 6;     // 0..7
  const int lane  = tid & 63;
  const int lrow  = lane & 31;
  const int lhalf = lane >> 5;

  const int blk = blockIdx.x;
  const int ks  = blk & 7;               // k-slice (XCD-pinned by dispatch % 8)
  const int qb  = blk >> 3;              // 0..31
  const int qw  = qb * 256 + wave * 32;  // wave's 32-row q base

  float* ws_l = (float*)(ws + WS_L_OFF);

  // ---- Q B-frags: lane holds Q[q=lane&31][d=(lane>>5)*8+j + 16s], scaled ----
  f16x8 qf[8];
  {
    const int q = qw + lrow;
    #pragma unroll
    for (int s = 0; s < 8; ++s) {
      const float4* src = (const float4*)(Qg + (size_t)q * D_K + s * 16 + lhalf * 8);
      float4 a = src[0], b = src[1];
      float f[8] = {a.x, a.y, a.z, a.w, b.x, b.y, b.z, b.w};
      UH8 h;
      #pragma unroll
      for (int j = 0; j < 8; ++j) h.h[j] = (_Float16)(f[j] * CSCALE);
      qf[s] = h.v;
    }
  }

  f32x16 O[4] = {f32x16{}, f32x16{}, f32x16{}, f32x16{}};
  float lsum = 0.f;

  const uint4* KVg = (const uint4*)(ws + KV_OFF);
  const size_t sbase = (size_t)ks * 32768;   // slice = 16 tiles x 2048 uint4

  // prologue: stage tile 0 into ring slot 0 (32 KB, 4 async16/thread)
  #pragma unroll
  for (int i = 0; i < 4; ++i)
    async16(KVg + sbase + i * 512 + tid, &KV[0][i * 512 + tid]);

  UF4 C00, C01, C10, C11;   // carried P-frags of tile t-1 (both subtiles)

  int cur = 0, nxt = 1;
  for (int it = 0; it < ITERS2; ++it) {
    __syncthreads();   // tile(it) staging (issued last iter) now complete

    if (it + 1 < ITERS2) {
      const size_t base = sbase + (size_t)(it + 1) * 2048;
      #pragma unroll
      for (int i = 0; i < 4; ++i)
        async16(KVg + base + i * 512 + tid, &KV[nxt][i * 512 + tid]);
    }

    // ---- QK(t): both subtiles, 4 independent dual-S chains ----
    f32x16 Sa0, Sb0, Sa1, Sb1;
    qk32(&KV[cur][0],    qf, lane, Sa0, Sb0);
    qk32(&KV[cur][1024], qf, lane, Sa1, Sb1);

    // ---- PV(t-1): independent of QK(t) -- overlaps QK's drain ----
    if (it) {
      const int prv = (cur == 0) ? 2 : cur - 1;
      pv32(&KV[prv][0],    C00, C01, lane, O);
      pv32(&KV[prv][1024], C10, C11, lane, O);
    }

    // ---- SM(t): VALU overlaps PV(t-1) MFMA drain; P carried to next iter ----
    softmax32(Sa0, Sb0, lsum, C00, C01);
    softmax32(Sa1, Sb1, lsum, C10, C11);

    cur = nxt;
    nxt = (nxt == 2) ? 0 : nxt + 1;
  }
  // epilogue drain: PV of the last tile
  {
    const int prv = (cur == 0) ? 2 : cur - 1;
    pv32(&KV[prv][0],    C00, C01, lane, O);
    pv32(&KV[prv][1024], C10, C11, lane, O);
  }

  // ---- epilogue ----
  lsum += __shfl_xor(lsum, 32);           // combine the two key-halves

  if (PARTIAL) {
    if (lhalf == 0) ws_l[ks * S_LEN + qw + lrow] = lsum;   // plain store
    float* obase = (ks == 0) ? out
                 : (float*)(ws + PART_OFF) + (size_t)(ks - 1) * S_LEN * D_K;
    #pragma unroll
    for (int r = 0; r < 16; ++r) {
      int row = (r & 3) + 8 * (r >> 2) + 4 * lhalf;
      float* dst = obase + (size_t)(qw + row) * D_K + lrow;
      dst[ 0] = O[0][r];
      dst[32] = O[1][r];
      dst[64] = O[2][r];
      dst[96] = O[3][r];
    }
  } else {
    if (lhalf == 0) atomicAdd(ws_l + qw + lrow, lsum);
    #pragma unroll
    for (int r = 0; r < 16; ++r) {
      int row = (r & 3) + 8 * (r >> 2) + 4 * lhalf;
      float* dst = out + (size_t)(qw + row) * D_K + lrow;
      atomicAdd(dst +  0, O[0][r]);
      atomicAdd(dst + 32, O[1][r]);
      atomicAdd(dst + 64, O[2][r]);
      atomicAdd(dst + 96, O[3][r]);
    }
  }
}

// ---------------- reduce partials (nparts>0) or just normalize (nparts=0) ----
__global__ __launch_bounds__(256) void attn_norm(float* __restrict__ out,
                                                 const float* __restrict__ lpart,
                                                 const float* __restrict__ opart,
                                                 int nparts) {
  int i = blockIdx.x * 256 + threadIdx.x;  // float4 index, 262144 total
  int q = i >> 5;
  float4* o4 = (float4*)out;
  float4 acc = o4[i];
  float l = lpart[q];
  for (int s = 1; s <= nparts; ++s) {
    float4 p = ((const float4*)opart)[(size_t)(s - 1) * 262144 + i];
    acc.x += p.x; acc.y += p.y; acc.z += p.z; acc.w += p.w;
    l += lpart[s * S_LEN + q];
  }
  float inv = 1.0f / l;
  acc.x *= inv; acc.y *= inv; acc.z *= inv; acc.w *= inv;
  o4[i] = acc;
}

extern "C" void kernel_launch(void* const* d_in, const int* in_sizes, int n_in,
                              void* d_out, int out_size, void* d_ws, size_t ws_size,
                              hipStream_t stream) {
  const float* q = (const float*)d_in[0];
  const float* k = (const float*)d_in[1];
  const float* v = (const float*)d_in[2];
  float* out = (float*)d_out;
  char* ws = (char*)d_ws;

  if (ws_size >= WS_NEED) {
    attn_prep<false><<<dim3(512), dim3(512), 0, stream>>>(k, v, out, ws);
    attn_main<true><<<dim3(256), dim3(512), 0, stream>>>(q, out, ws);
    attn_norm<<<dim3(1024), dim3(256), 0, stream>>>(
        out, (const float*)(ws + WS_L_OFF), (const float*)(ws + PART_OFF), 7);
  } else {
    attn_prep<true><<<dim3(645), dim3(512), 0, stream>>>(k, v, out, ws);
    attn_main<false><<<dim3(256), dim3(512), 0, stream>>>(q, out, ws);
    attn_norm<<<dim3(1024), dim3(256), 0, stream>>>(
        out, (const float*)(ws + WS_L_OFF), (const float*)(ws + PART_OFF), 0);
  }
}

// Round 14
// 110.863 us; speedup vs baseline: 1.7591x; 1.0107x over previous
//
#include <hip/hip_runtime.h>
#include <math.h>

// fp16-MFMA flash attention (no-max softmax), S=8192, D=128, fp32 in/out.
// R27 = R22 exact restore (session best: 45.4us main / 109.8 total).
// R26's isolated A/B proved s_setprio on MFMA clusters is worth +3.3us in
// THIS structure (45.4 -> 48.7 without it): R22's ring-3 interleave slides
// co-resident waves' QK/PV/SM phases against each other between barriers,
// so MFMA-priority does arbitrate (m190's null was for lockstep loops).
// Closed axes (all measured): scheduling/phase (R15/R16/R23 null-or-worse),
// intensity 2MFMA/read (R14/R17/R20 spill at the 128arch+128acc/wave
// envelope; acc file exactly full at 32q/wave), occupancy (R19 null),
// LDS-traffic cut (R21 null), prep/norm fusion (R24/R25 cost > ~13us/
// dispatch saved). Structure is latency-bound with pipes summing at
// ~30/25/45% -- remaining escapes need register budgets this HW doesn't
// offer at 2 waves/SIMD. ~54us fixed harness overhead is outside kernel
// control.
// Structure: ring-3 LDS pipeline QK(t)||PV(t-1)||SM(t) with carried P-frags
// (one-tile skew), permlane32_swap softmax transpose, transposed-S fp16
// QK^T (A=K,B=Q), dual-S 4-deep MFMA chains, async global_load_lds staging,
// setprio(1) around MFMA clusters, 8-slice partial stores + reduce/norm.
// Graveyard: R8/R11 fusion, R9/R6 16-slice, R10 direct L2->reg, R14/R17/R20
// 64q/wave (spills), R15 stagger, R16 phase rotation, R18 restructure
// (correctness), R19 4 waves/SIMD, R21 traffic cut, R23 producer/consumer
// (2.8x), R24 prep fusion (+21.6us), R25 norm fusion (+94us), R26 setprio
// removal (+3.3us).

typedef _Float16 f16x8 __attribute__((ext_vector_type(8)));
typedef float    f32x16 __attribute__((ext_vector_type(16)));

constexpr int S_LEN = 8192;
constexpr int D_K   = 128;
constexpr int NSLICE = 8;
constexpr int ITERS2 = (S_LEN / NSLICE) / 64;   // 16 iters of 64-key tiles

// ws: Lpart[8][8192] fp32 (256 KB) | KV frags (4 MB) | Opart[7] x 4 MB
constexpr size_t WS_L_OFF = 0;
constexpr size_t KV_OFF   = 262144;
constexpr size_t PART_OFF = KV_OFF + (size_t)256 * 16384;
constexpr size_t WS_NEED  = PART_OFF + (size_t)7 * S_LEN * D_K * 4;  // ~32.5 MB

#define CSCALE (0.08838834764831845f * 1.44269504088896340736f)

union UH8 { _Float16 h[8]; uint4 q; f16x8 v; };
union UF4 { unsigned u[4]; uint4 q; f16x8 v; };

__device__ inline void async16(const uint4* g, uint4* l) {
  __builtin_amdgcn_global_load_lds(
      (const __attribute__((address_space(1))) unsigned int*)g,
      (__attribute__((address_space(3))) unsigned int*)l, 16, 0, 0);
}

// ---------------- prep: frag build (+ zero out/ws_l if atomic path) ----------
template <bool ZOUT>
__global__ __launch_bounds__(512) void attn_prep(const float* __restrict__ K,
                                                 const float* __restrict__ V,
                                                 float* __restrict__ out,
                                                 char* __restrict__ ws) {
  const int t = blockIdx.x * 512 + threadIdx.x;
  uint4* KVg = (uint4*)(ws + KV_OFF);
  if (t < 131072) {
    // K frag: lane holds K[key=lane&31][d0..d0+7], d0 = s*16 + (lane>>5)*8
    int kt = t >> 9, idx = t & 511;
    int lane = idx & 63, s = idx >> 6;
    int key = kt * 32 + (lane & 31);
    int d0  = s * 16 + (lane >> 5) * 8;
    const float4* src = (const float4*)(K + (size_t)key * D_K + d0);
    float4 a = src[0], b = src[1];
    float f[8] = {a.x, a.y, a.z, a.w, b.x, b.y, b.z, b.w};
    UH8 h;
    #pragma unroll
    for (int j = 0; j < 8; ++j) h.h[j] = (_Float16)f[j];
    KVg[(size_t)kt * 1024 + idx] = h.q;
  } else if (t < 262144) {
    // V frag: lane holds V[kb..kb+7][d], d = c*32 + (lane&31)
    int g = t - 131072;
    int kt = g >> 9, idx = g & 511;
    int lane = idx & 63, c = (idx >> 6) & 3, kstep = idx >> 8;
    int d  = c * 32 + (lane & 31);
    int kb = kt * 32 + kstep * 16 + (lane >> 5) * 8;
    UH8 h;
    #pragma unroll
    for (int j = 0; j < 8; ++j) h.h[j] = (_Float16)V[(size_t)(kb + j) * D_K + d];
    KVg[(size_t)kt * 1024 + 512 + idx] = h.q;
  } else if (ZOUT && t < 327680) {
    int i = t - 262144;  // zero out: 65536 threads x 4 float4
    float4 z = make_float4(0.f, 0.f, 0.f, 0.f);
    float4* o4 = (float4*)out;
    #pragma unroll
    for (int j = 0; j < 4; ++j) o4[(size_t)i * 4 + j] = z;
  } else if (ZOUT && t < 329728) {
    int i = t - 327680;  // zero ws_l: 2048 float4
    ((float4*)(ws + WS_L_OFF))[i] = make_float4(0.f, 0.f, 0.f, 0.f);
  }
}

// QK^T over one 32-key subtile: 8 K-frag ds_reads feeding 2 interleaved
// 4-deep MFMA chains (Sa even d-slices, Sb odd).
__device__ inline void qk32(const uint4* sub, const f16x8* qf, int lane,
                            f32x16& Sa, f32x16& Sb) {
  Sa = f32x16{}; Sb = f32x16{};
  __builtin_amdgcn_s_setprio(1);
  #pragma unroll
  for (int s = 0; s < 4; ++s) {
    f16x8 ka = __builtin_bit_cast(f16x8, sub[(2 * s    ) * 64 + lane]);
    f16x8 kb = __builtin_bit_cast(f16x8, sub[(2 * s + 1) * 64 + lane]);
    Sa = __builtin_amdgcn_mfma_f32_32x32x16_f16(ka, qf[2 * s    ], Sa, 0, 0, 0);
    Sb = __builtin_amdgcn_mfma_f32_32x32x16_f16(kb, qf[2 * s + 1], Sb, 0, 0, 0);
  }
  __builtin_amdgcn_s_setprio(0);
}

// softmax over one 32-key subtile: Sa+Sb -> exp2 -> packed fp16 P frags
// (A0 = keys 0..15, A1 = keys 16..31), accumulating row-sum.
// P transpose via v_permlane32_swap (R15-verified lane mapping).
__device__ inline void softmax32(const f32x16& Sa, const f32x16& Sb,
                                 float& lsum, UF4& A0, UF4& A1) {
  unsigned pk[8];
  #pragma unroll
  for (int i = 0; i < 8; ++i) {
    float p0 = __builtin_amdgcn_exp2f(Sa[2 * i]     + Sb[2 * i]);
    float p1 = __builtin_amdgcn_exp2f(Sa[2 * i + 1] + Sb[2 * i + 1]);
    lsum += p0 + p1;
    pk[i] = __builtin_bit_cast(unsigned, __builtin_amdgcn_cvt_pkrtz(p0, p1));
  }
  auto r0 = __builtin_amdgcn_permlane32_swap((int)pk[0], (int)pk[2], false, false);
  auto r1 = __builtin_amdgcn_permlane32_swap((int)pk[1], (int)pk[3], false, false);
  auto r2 = __builtin_amdgcn_permlane32_swap((int)pk[4], (int)pk[6], false, false);
  auto r3 = __builtin_amdgcn_permlane32_swap((int)pk[5], (int)pk[7], false, false);
  A0.u[0] = (unsigned)r0[0]; A0.u[2] = (unsigned)r0[1];
  A0.u[1] = (unsigned)r1[0]; A0.u[3] = (unsigned)r1[1];
  A1.u[0] = (unsigned)r2[0]; A1.u[2] = (unsigned)r2[1];
  A1.u[1] = (unsigned)r3[0]; A1.u[3] = (unsigned)r3[1];
}

// PV over one 32-key subtile: 8 V-frag ds_reads feeding 8 MFMAs (4 indep O).
__device__ inline void pv32(const uint4* sub, const UF4& A0, const UF4& A1,
                            int lane, f32x16* O) {
  __builtin_amdgcn_s_setprio(1);
  #pragma unroll
  for (int kstep = 0; kstep < 2; ++kstep) {
    f16x8 pf = kstep ? A1.v : A0.v;
    f16x8 v0 = __builtin_bit_cast(f16x8, sub[512 + kstep * 256 +   0 + lane]);
    f16x8 v1 = __builtin_bit_cast(f16x8, sub[512 + kstep * 256 +  64 + lane]);
    f16x8 v2 = __builtin_bit_cast(f16x8, sub[512 + kstep * 256 + 128 + lane]);
    f16x8 v3 = __builtin_bit_cast(f16x8, sub[512 + kstep * 256 + 192 + lane]);
    O[0] = __builtin_amdgcn_mfma_f32_32x32x16_f16(pf, v0, O[0], 0, 0, 0);
    O[1] = __builtin_amdgcn_mfma_f32_32x32x16_f16(pf, v1, O[1], 0, 0, 0);
    O[2] = __builtin_amdgcn_mfma_f32_32x32x16_f16(pf, v2, O[2], 0, 0, 0);
    O[3] = __builtin_amdgcn_mfma_f32_32x32x16_f16(pf, v3, O[3], 0, 0, 0);
  }
  __builtin_amdgcn_s_setprio(0);
}

// ---------------- main attention kernel ----------------
template <bool PARTIAL>
__global__ __launch_bounds__(512, 2)
void attn_main(const float* __restrict__ Qg, float* __restrict__ out,
               char* __restrict__ ws) {
  __shared__ uint4 KV[3][2048];   // ring-3 of 64-key tiles [K 16KB | V 16KB]

  const int tid   = threadIdx.x;
  const int wave  = tid >> 6;     // 0..7
  const int lane  = tid & 63;
  const int lrow  = lane & 31;
  const int lhalf = lane >> 5;

  const int blk = blockIdx.x;
  const int ks  = blk & 7;               // k-slice (XCD-pinned by dispatch % 8)
  const int qb  = blk >> 3;              // 0..31
  const int qw  = qb * 256 + wave * 32;  // wave's 32-row q base

  float* ws_l = (float*)(ws + WS_L_OFF);

  // ---- Q B-frags: lane holds Q[q=lane&31][d=(lane>>5)*8+j + 16s], scaled ----
  f16x8 qf[8];
  {
    const int q = qw + lrow;
    #pragma unroll
    for (int s = 0; s < 8; ++s) {
      const float4* src = (const float4*)(Qg + (size_t)q * D_K + s * 16 + lhalf * 8);
      float4 a = src[0], b = src[1];
      float f[8] = {a.x, a.y, a.z, a.w, b.x, b.y, b.z, b.w};
      UH8 h;
      #pragma unroll
      for (int j = 0; j < 8; ++j) h.h[j] = (_Float16)(f[j] * CSCALE);
      qf[s] = h.v;
    }
  }

  f32x16 O[4] = {f32x16{}, f32x16{}, f32x16{}, f32x16{}};
  float lsum = 0.f;

  const uint4* KVg = (const uint4*)(ws + KV_OFF);
  const size_t sbase = (size_t)ks * 32768;   // slice = 16 tiles x 2048 uint4

  // prologue: stage tile 0 into ring slot 0 (32 KB, 4 async16/thread)
  #pragma unroll
  for (int i = 0; i < 4; ++i)
    async16(KVg + sbase + i * 512 + tid, &KV[0][i * 512 + tid]);

  UF4 C00, C01, C10, C11;   // carried P-frags of tile t-1 (both subtiles)

  int cur = 0, nxt = 1;
  for (int it = 0; it < ITERS2; ++it) {
    __syncthreads();   // tile(it) staging (issued last iter) now complete

    if (it + 1 < ITERS2) {
      const size_t base = sbase + (size_t)(it + 1) * 2048;
      #pragma unroll
      for (int i = 0; i < 4; ++i)
        async16(KVg + base + i * 512 + tid, &KV[nxt][i * 512 + tid]);
    }

    // ---- QK(t): both subtiles, 4 independent dual-S chains ----
    f32x16 Sa0, Sb0, Sa1, Sb1;
    qk32(&KV[cur][0],    qf, lane, Sa0, Sb0);
    qk32(&KV[cur][1024], qf, lane, Sa1, Sb1);

    // ---- PV(t-1): independent of QK(t) -- overlaps QK's drain ----
    if (it) {
      const int prv = (cur == 0) ? 2 : cur - 1;
      pv32(&KV[prv][0],    C00, C01, lane, O);
      pv32(&KV[prv][1024], C10, C11, lane, O);
    }

    // ---- SM(t): VALU overlaps PV(t-1) MFMA drain; P carried to next iter ----
    softmax32(Sa0, Sb0, lsum, C00, C01);
    softmax32(Sa1, Sb1, lsum, C10, C11);

    cur = nxt;
    nxt = (nxt == 2) ? 0 : nxt + 1;
  }
  // epilogue drain: PV of the last tile
  {
    const int prv = (cur == 0) ? 2 : cur - 1;
    pv32(&KV[prv][0],    C00, C01, lane, O);
    pv32(&KV[prv][1024], C10, C11, lane, O);
  }

  // ---- epilogue ----
  lsum += __shfl_xor(lsum, 32);           // combine the two key-halves

  if (PARTIAL) {
    if (lhalf == 0) ws_l[ks * S_LEN + qw + lrow] = lsum;   // plain store
    float* obase = (ks == 0) ? out
                 : (float*)(ws + PART_OFF) + (size_t)(ks - 1) * S_LEN * D_K;
    #pragma unroll
    for (int r = 0; r < 16; ++r) {
      int row = (r & 3) + 8 * (r >> 2) + 4 * lhalf;
      float* dst = obase + (size_t)(qw + row) * D_K + lrow;
      dst[ 0] = O[0][r];
      dst[32] = O[1][r];
      dst[64] = O[2][r];
      dst[96] = O[3][r];
    }
  } else {
    if (lhalf == 0) atomicAdd(ws_l + qw + lrow, lsum);
    #pragma unroll
    for (int r = 0; r < 16; ++r) {
      int row = (r & 3) + 8 * (r >> 2) + 4 * lhalf;
      float* dst = out + (size_t)(qw + row) * D_K + lrow;
      atomicAdd(dst +  0, O[0][r]);
      atomicAdd(dst + 32, O[1][r]);
      atomicAdd(dst + 64, O[2][r]);
      atomicAdd(dst + 96, O[3][r]);
    }
  }
}

// ---------------- reduce partials (nparts>0) or just normalize (nparts=0) ----
__global__ __launch_bounds__(256) void attn_norm(float* __restrict__ out,
                                                 const float* __restrict__ lpart,
                                                 const float* __restrict__ opart,
                                                 int nparts) {
  int i = blockIdx.x * 256 + threadIdx.x;  // float4 index, 262144 total
  int q = i >> 5;
  float4* o4 = (float4*)out;
  float4 acc = o4[i];
  float l = lpart[q];
  for (int s = 1; s <= nparts; ++s) {
    float4 p = ((const float4*)opart)[(size_t)(s - 1) * 262144 + i];
    acc.x += p.x; acc.y += p.y; acc.z += p.z; acc.w += p.w;
    l += lpart[s * S_LEN + q];
  }
  float inv = 1.0f / l;
  acc.x *= inv; acc.y *= inv; acc.z *= inv; acc.w *= inv;
  o4[i] = acc;
}

extern "C" void kernel_launch(void* const* d_in, const int* in_sizes, int n_in,
                              void* d_out, int out_size, void* d_ws, size_t ws_size,
                              hipStream_t stream) {
  const float* q = (const float*)d_in[0];
  const float* k = (const float*)d_in[1];
  const float* v = (const float*)d_in[2];
  float* out = (float*)d_out;
  char* ws = (char*)d_ws;

  if (ws_size >= WS_NEED) {
    attn_prep<false><<<dim3(512), dim3(512), 0, stream>>>(k, v, out, ws);
    attn_main<true><<<dim3(256), dim3(512), 0, stream>>>(q, out, ws);
    attn_norm<<<dim3(1024), dim3(256), 0, stream>>>(
        out, (const float*)(ws + WS_L_OFF), (const float*)(ws + PART_OFF), 7);
  } else {
    attn_prep<true><<<dim3(645), dim3(512), 0, stream>>>(k, v, out, ws);
    attn_main<false><<<dim3(512), dim3(256), 0, stream>>>(q, out, ws);
    attn_norm<<<dim3(1024), dim3(256), 0, stream>>>(
        out, (const float*)(ws + WS_L_OFF), (const float*)(ws + PART_OFF), 0);
  }
}